// Round 19
// baseline (392.165 us; speedup 1.0000x reference)
//
#include <hip/hip_runtime.h>
#include <hip/hip_bf16.h>

typedef __attribute__((ext_vector_type(4))) float floatx4;
typedef __attribute__((ext_vector_type(8))) short short8;
typedef __attribute__((ext_vector_type(8))) unsigned short ushortx8;

#define K1 2048
#define N1 1024
#define K2 1024
#define N2 1024

__device__ __forceinline__ unsigned short f2bf(float f) {
  __hip_bfloat16 h = __float2bfloat16(f);
  return __builtin_bit_cast(unsigned short, h);
}

__device__ __forceinline__ void gload_lds16(const void* g, void* l) {
  __builtin_amdgcn_global_load_lds(
      (__attribute__((address_space(1))) void*)const_cast<void*>(g),
      (__attribute__((address_space(3))) void*)l, 16, 0, 0);
}

// merged W1+W2 fp32->bf16 convert
__global__ __launch_bounds__(256) void cvt2_kernel(
    const float* __restrict__ W1, const float* __restrict__ W2,
    unsigned short* __restrict__ W1b, unsigned short* __restrict__ W2b) {
  int i = blockIdx.x * blockDim.x + threadIdx.x;
  const float* src;
  unsigned short* dst;
  if (i < 524288) {
    src = (const float*)&reinterpret_cast<const float4*>(W1)[i];
    dst = (unsigned short*)&reinterpret_cast<ushort4*>(W1b)[i];
  } else {
    int k = i - 524288;
    if (k >= 262144) return;
    src = (const float*)&reinterpret_cast<const float4*>(W2)[k];
    dst = (unsigned short*)&reinterpret_cast<ushort4*>(W2b)[k];
  }
  float4 f = *reinterpret_cast<const float4*>(src);
  ushort4 o;
  o.x = f2bf(f.x); o.y = f2bf(f.y); o.z = f2bf(f.z); o.w = f2bf(f.w);
  *reinterpret_cast<ushort4*>(dst) = o;
}

// GEMM1 + fused gather: h = gelu(bf16(tok[idx]) @ W1^T + b1).
// r17 structure + (a) 2-deep A register prefetch (avA/avB, manual 2x unroll,
// static indexing) and (b) counted boundary vmcnt(8) — the 8 newest
// outstanding vmem ops are PRIVATE register loads (tile tt+2's A), so the
// barrier only needs the older B gload_lds retired. LDS-transpose epilogue.
__global__ __launch_bounds__(512, 2) void gemm1_fused_kernel(
    const int* __restrict__ idxs, const float* __restrict__ tok,
    const unsigned short* __restrict__ W1b, const float* __restrict__ b1,
    unsigned short* __restrict__ hout) {
  __shared__ unsigned short S[65536];  // loop: A 2x16384 | B 2x16384; epi: 8x8192
  const int t = threadIdx.x;
  const int p = blockIdx.x;
  const int bid = (p & 7) * 32 + (p >> 3);  // XCD owns contiguous bm range
  const int bm = bid >> 2, bn = bid & 3;
  const int brow0 = bm * 256, bcol0 = bn * 256;
  const int lane = t & 63, w = t >> 6;
  const int wm = w >> 2, wn = w & 3;  // per-wave C: 128x64
  const int fr = lane & 15, kg2 = lane >> 4;

  const int srow = t >> 3;
  const int cg = (t & 7) ^ (srow & 7);
  const float* aqf[4];
  const unsigned short* bq[4];
#pragma unroll
  for (int q = 0; q < 4; ++q) {
    const int ridx = idxs[brow0 + srow + 64 * q];
    aqf[q] = tok + (size_t)ridx * K1 + cg * 8;
    bq[q] = W1b + (size_t)(bcol0 + srow + 64 * q) * K1 + cg * 8;
  }
  const int t8 = t * 8;

  floatx4 acc[8][4] = {};
  constexpr int NT = K1 / 64;  // 32 (even)

  float4 avA[4][2], avB[4][2];
  auto loadTo = [&](float4 (&dst)[4][2], int k0) {
#pragma unroll
    for (int q = 0; q < 4; ++q) {
      dst[q][0] = *reinterpret_cast<const float4*>(aqf[q] + k0);
      dst[q][1] = *reinterpret_cast<const float4*>(aqf[q] + k0 + 4);
    }
  };
  auto writeAv = [&](int d, const float4 (&src)[4][2]) {
#pragma unroll
    for (int q = 0; q < 4; ++q) {
      ushortx8 u;
      u[0] = f2bf(src[q][0].x); u[1] = f2bf(src[q][0].y);
      u[2] = f2bf(src[q][0].z); u[3] = f2bf(src[q][0].w);
      u[4] = f2bf(src[q][1].x); u[5] = f2bf(src[q][1].y);
      u[6] = f2bf(src[q][1].z); u[7] = f2bf(src[q][1].w);
      *reinterpret_cast<ushortx8*>(&S[d * 16384 + t8 + q * 4096]) = u;
    }
  };
  auto issueB = [&](int d, int k0) {
#pragma unroll
    for (int q = 0; q < 4; ++q)
      gload_lds16(bq[q] + k0, &S[32768 + d * 16384 + t8 + q * 4096]);
  };
  auto computeKS = [&](int cur, int ks) {
    const int sl = ((ks * 4 + kg2) ^ (fr & 7)) * 8;
    short8 bf[4];
#pragma unroll
    for (int j = 0; j < 4; ++j)
      bf[j] = *(const short8*)&S[32768 + cur * 16384 + (wn * 64 + j * 16 + fr) * 64 + sl];
    __builtin_amdgcn_s_setprio(1);
#pragma unroll
    for (int i = 0; i < 8; ++i) {
      const short8 af = *(const short8*)&S[cur * 16384 + (wm * 128 + i * 16 + fr) * 64 + sl];
#pragma unroll
      for (int j = 0; j < 4; ++j)
        acc[i][j] = __builtin_amdgcn_mfma_f32_16x16x32_bf16(af, bf[j], acc[i][j], 0, 0, 0);
    }
    __builtin_amdgcn_s_setprio(0);
  };

  // prologue: tile 0 staged via temp; tile 1's A pre-loaded into avB.
  {
    float4 tv[4][2];
    loadTo(tv, 0);
    issueB(0, 0);
    loadTo(avB, 64);
    writeAv(0, tv);
    asm volatile("s_waitcnt vmcnt(0) lgkmcnt(0)\ns_barrier" ::: "memory");
  }

#pragma unroll 1
  for (int t2 = 0; t2 < NT; t2 += 2) {
    // ---- even iter: tt = t2, cur = 0, nbuf = 1; tile tt+1 A in avB ----
    {
      const int tt = t2;
      const bool pf2 = (tt + 2 < NT);
      issueB(1, (tt + 1) * 64);          // tt+1 < NT always (NT even)
      computeKS(0, 0);
      writeAv(1, avB);                   // loaded a full iter ago: no stall
      if (pf2) loadTo(avA, (tt + 2) * 64);
      computeKS(0, 1);
      if (pf2)  // newest 8 = private avA loads; retire only the older B ops
        asm volatile("s_waitcnt vmcnt(8) lgkmcnt(0)\ns_barrier" ::: "memory");
      else
        asm volatile("s_waitcnt vmcnt(0) lgkmcnt(0)\ns_barrier" ::: "memory");
    }
    // ---- odd iter: tt = t2+1, cur = 1, nbuf = 0; tile tt+1 A in avA ----
    {
      const int tt = t2 + 1;
      const bool pf = (tt + 1 < NT);
      const bool pf2 = (tt + 2 < NT);
      if (pf) issueB(0, (tt + 1) * 64);
      computeKS(1, 0);
      if (pf) writeAv(0, avA);
      if (pf2) loadTo(avB, (tt + 2) * 64);
      computeKS(1, 1);
      if (pf2)
        asm volatile("s_waitcnt vmcnt(8) lgkmcnt(0)\ns_barrier" ::: "memory");
      else
        asm volatile("s_waitcnt vmcnt(0) lgkmcnt(0)\ns_barrier" ::: "memory");
    }
  }

  // epilogue: bias + exact GELU -> LDS (chunk-XOR swizzled) -> coalesced store
  const int ec0 = bcol0 + wn * 64 + fr;
  float bv[4];
#pragma unroll
  for (int j = 0; j < 4; ++j) bv[j] = b1[ec0 + j * 16];
  unsigned short* Wl = S + w * 8192;  // this wave's 128x64 region
#pragma unroll
  for (int i = 0; i < 8; ++i)
#pragma unroll
    for (int j = 0; j < 4; ++j)
#pragma unroll
      for (int r = 0; r < 4; ++r) {
        float v = acc[i][j][r] + bv[j];
        v = 0.5f * v * (1.0f + erff(v * 0.70710678118654752f));
        const int row = i * 16 + kg2 * 4 + r;
        const int col = (j * 16 + fr) ^ (kg2 << 3);  // chunk-XOR swizzle
        Wl[row * 64 + col] = f2bf(v);
      }
  asm volatile("s_waitcnt lgkmcnt(0)" ::: "memory");
#pragma unroll
  for (int pass = 0; pass < 16; ++pass) {  // 16 passes x 8 rows = 128 rows
    const int wr = pass * 8 + (lane >> 3);
    const int ch = (lane & 7) ^ ((wr >> 2) & 3);  // unswizzle chunk
    const short8 v8 = *(const short8*)&Wl[wr * 64 + ch * 8];
    *reinterpret_cast<short8*>(
        &hout[(size_t)(brow0 + wm * 128 + wr) * N1 + bcol0 + wn * 64 + (lane & 7) * 8]) = v8;
  }
}

// GEMM2 (r17 verbatim): out = h @ W2^T + b2 (fp32), 2-phase loop +
// LDS-transpose epilogue.
__global__ __launch_bounds__(512, 2) void gemm2_kernel(
    const unsigned short* __restrict__ A, const unsigned short* __restrict__ Bw,
    const float* __restrict__ bias, float* __restrict__ out) {
  __shared__ unsigned short S[65536];
  const int t = threadIdx.x;
  const int p = blockIdx.x;
  const int bid = (p & 7) * 32 + (p >> 3);
  const int bm = bid >> 2, bn = bid & 3;
  const int brow0 = bm * 256, bcol0 = bn * 256;
  const int lane = t & 63, w = t >> 6;
  const int wm = w >> 2, wn = w & 3;
  const int fr = lane & 15, kg2 = lane >> 4;

  const int srow = t >> 3;
  const int cg = (t & 7) ^ (srow & 7);
  const unsigned short* aq[4];
  const unsigned short* bq[4];
#pragma unroll
  for (int q = 0; q < 4; ++q) {
    aq[q] = A + (size_t)(brow0 + srow + 64 * q) * K2 + cg * 8;
    bq[q] = Bw + (size_t)(bcol0 + srow + 64 * q) * K2 + cg * 8;
  }
  const int t8 = t * 8;

  floatx4 acc[8][4] = {};
  constexpr int NT = K2 / 64;

  auto stage = [&](int d, int k0) {
#pragma unroll
    for (int q = 0; q < 4; ++q) {
      gload_lds16(aq[q] + k0, &S[d * 16384 + t8 + q * 4096]);
      gload_lds16(bq[q] + k0, &S[32768 + d * 16384 + t8 + q * 4096]);
    }
  };
  auto compute = [&](int cur) {
#pragma unroll
    for (int ks = 0; ks < 2; ++ks) {
      const int sl = ((ks * 4 + kg2) ^ (fr & 7)) * 8;
      short8 bf[4];
#pragma unroll
      for (int j = 0; j < 4; ++j)
        bf[j] = *(const short8*)&S[32768 + cur * 16384 + (wn * 64 + j * 16 + fr) * 64 + sl];
      __builtin_amdgcn_s_setprio(1);
#pragma unroll
      for (int i = 0; i < 8; ++i) {
        const short8 af = *(const short8*)&S[cur * 16384 + (wm * 128 + i * 16 + fr) * 64 + sl];
#pragma unroll
        for (int j = 0; j < 4; ++j)
          acc[i][j] = __builtin_amdgcn_mfma_f32_16x16x32_bf16(af, bf[j], acc[i][j], 0, 0, 0);
      }
      __builtin_amdgcn_s_setprio(0);
    }
  };

  stage(0, 0);
#pragma unroll 1
  for (int it = 0; it < NT - 1; ++it) {
    const int cur = it & 1;
    stage(cur ^ 1, (it + 1) * 64);
    asm volatile("s_waitcnt vmcnt(8)\ns_barrier" ::: "memory");
    compute(cur);
    asm volatile("s_waitcnt lgkmcnt(0)\ns_barrier" ::: "memory");
  }
  asm volatile("s_waitcnt vmcnt(0)\ns_barrier" ::: "memory");
  compute((NT - 1) & 1);
  asm volatile("s_waitcnt lgkmcnt(0)\ns_barrier" ::: "memory");

  const int ec0 = bcol0 + wn * 64 + fr;
  float bv[4];
#pragma unroll
  for (int j = 0; j < 4; ++j) bv[j] = bias[ec0 + j * 16];
  float* Wf = reinterpret_cast<float*>(S) + w * 4096;
#pragma unroll
  for (int ih = 0; ih < 2; ++ih) {
#pragma unroll
    for (int i4 = 0; i4 < 4; ++i4)
#pragma unroll
      for (int j = 0; j < 4; ++j)
#pragma unroll
        for (int r = 0; r < 4; ++r) {
          const int row = i4 * 16 + kg2 * 4 + r;
          const int col = (j * 16 + fr) ^ (kg2 << 2);
          Wf[row * 64 + col] = acc[ih * 4 + i4][j][r] + bv[j];
        }
    asm volatile("s_waitcnt lgkmcnt(0)" ::: "memory");
#pragma unroll
    for (int pass = 0; pass < 16; ++pass) {
      const int wr = pass * 4 + (lane >> 4);
      const int ch = (lane & 15) ^ ((wr >> 2) & 3);
      const floatx4 v4 = *(const floatx4*)&Wf[wr * 64 + ch * 4];
      *reinterpret_cast<floatx4*>(
          &out[(size_t)(brow0 + wm * 128 + ih * 64 + wr) * N2 + bcol0 + wn * 64 +
               (lane & 15) * 4]) = v4;
    }
    if (ih == 0)
      asm volatile("s_waitcnt lgkmcnt(0)" ::: "memory");
  }
}

extern "C" void kernel_launch(void* const* d_in, const int* in_sizes, int n_in,
                              void* d_out, int out_size, void* d_ws, size_t ws_size,
                              hipStream_t stream) {
  const int* idxs = (const int*)d_in[0];
  const float* tok = (const float*)d_in[1];
  const float* W1 = (const float*)d_in[2];
  const float* b1 = (const float*)d_in[3];
  const float* W2 = (const float*)d_in[4];
  const float* b2 = (const float*)d_in[5];
  float* out = (float*)d_out;

  unsigned short* W1b = (unsigned short*)d_ws;                          // 4 MB
  unsigned short* W2b = (unsigned short*)((char*)d_ws + (4u << 20));    // 2 MB
  unsigned short* hbuf = (unsigned short*)((char*)d_ws + (6u << 20));   // 32 MB

  cvt2_kernel<<<3072, 256, 0, stream>>>(W1, W2, W1b, W2b);
  gemm1_fused_kernel<<<256, 512, 0, stream>>>(idxs, tok, W1b, b1, hbuf);
  gemm2_kernel<<<256, 512, 0, stream>>>(hbuf, W2b, b2, out);
}

// Round 20
// 141.386 us; speedup vs baseline: 2.7737x; 2.7737x over previous
//
#include <hip/hip_runtime.h>
#include <hip/hip_bf16.h>

// Round 20: exact revert to round 17 (best, 140.9 µs). r19's av-prefetch
// overflowed the VGPR budget -> scratch spills (WRITE_SIZE 697 MB, 392 µs).

typedef __attribute__((ext_vector_type(4))) float floatx4;
typedef __attribute__((ext_vector_type(8))) short short8;
typedef __attribute__((ext_vector_type(8))) unsigned short ushortx8;

#define K1 2048
#define N1 1024
#define K2 1024
#define N2 1024

__device__ __forceinline__ unsigned short f2bf(float f) {
  __hip_bfloat16 h = __float2bfloat16(f);
  return __builtin_bit_cast(unsigned short, h);
}

__device__ __forceinline__ void gload_lds16(const void* g, void* l) {
  __builtin_amdgcn_global_load_lds(
      (__attribute__((address_space(1))) void*)const_cast<void*>(g),
      (__attribute__((address_space(3))) void*)l, 16, 0, 0);
}

// merged W1+W2 fp32->bf16 convert
__global__ __launch_bounds__(256) void cvt2_kernel(
    const float* __restrict__ W1, const float* __restrict__ W2,
    unsigned short* __restrict__ W1b, unsigned short* __restrict__ W2b) {
  int i = blockIdx.x * blockDim.x + threadIdx.x;
  const float* src;
  unsigned short* dst;
  if (i < 524288) {
    src = (const float*)&reinterpret_cast<const float4*>(W1)[i];
    dst = (unsigned short*)&reinterpret_cast<ushort4*>(W1b)[i];
  } else {
    int k = i - 524288;
    if (k >= 262144) return;
    src = (const float*)&reinterpret_cast<const float4*>(W2)[k];
    dst = (unsigned short*)&reinterpret_cast<ushort4*>(W2b)[k];
  }
  float4 f = *reinterpret_cast<const float4*>(src);
  ushort4 o;
  o.x = f2bf(f.x); o.y = f2bf(f.y); o.z = f2bf(f.z); o.w = f2bf(f.w);
  *reinterpret_cast<ushort4*>(dst) = o;
}

// GEMM1 + fused gather: h = gelu(bf16(tok[idx]) @ W1^T + b1).
__global__ __launch_bounds__(512, 2) void gemm1_fused_kernel(
    const int* __restrict__ idxs, const float* __restrict__ tok,
    const unsigned short* __restrict__ W1b, const float* __restrict__ b1,
    unsigned short* __restrict__ hout) {
  __shared__ unsigned short S[65536];  // loop: A 2x16384 | B 2x16384; epi: 8x8192
  const int t = threadIdx.x;
  const int p = blockIdx.x;
  const int bid = (p & 7) * 32 + (p >> 3);  // XCD owns contiguous bm range
  const int bm = bid >> 2, bn = bid & 3;
  const int brow0 = bm * 256, bcol0 = bn * 256;
  const int lane = t & 63, w = t >> 6;
  const int wm = w >> 2, wn = w & 3;  // per-wave C: 128x64
  const int fr = lane & 15, kg2 = lane >> 4;

  const int srow = t >> 3;
  const int cg = (t & 7) ^ (srow & 7);
  const float* aqf[4];
  const unsigned short* bq[4];
#pragma unroll
  for (int q = 0; q < 4; ++q) {
    const int ridx = idxs[brow0 + srow + 64 * q];
    aqf[q] = tok + (size_t)ridx * K1 + cg * 8;
    bq[q] = W1b + (size_t)(bcol0 + srow + 64 * q) * K1 + cg * 8;
  }
  const int t8 = t * 8;

  floatx4 acc[8][4] = {};
  constexpr int NT = K1 / 64;

  float4 av[4][2];
  auto loadA = [&](int k0) {
#pragma unroll
    for (int q = 0; q < 4; ++q) {
      av[q][0] = *reinterpret_cast<const float4*>(aqf[q] + k0);
      av[q][1] = *reinterpret_cast<const float4*>(aqf[q] + k0 + 4);
    }
  };
  auto writeA = [&](int d) {
#pragma unroll
    for (int q = 0; q < 4; ++q) {
      ushortx8 u;
      u[0] = f2bf(av[q][0].x); u[1] = f2bf(av[q][0].y);
      u[2] = f2bf(av[q][0].z); u[3] = f2bf(av[q][0].w);
      u[4] = f2bf(av[q][1].x); u[5] = f2bf(av[q][1].y);
      u[6] = f2bf(av[q][1].z); u[7] = f2bf(av[q][1].w);
      *reinterpret_cast<ushortx8*>(&S[d * 16384 + t8 + q * 4096]) = u;
    }
  };
  auto issueB = [&](int d, int k0) {
#pragma unroll
    for (int q = 0; q < 4; ++q)
      gload_lds16(bq[q] + k0, &S[32768 + d * 16384 + t8 + q * 4096]);
  };
  auto computeKS = [&](int cur, int ks) {
    const int sl = ((ks * 4 + kg2) ^ (fr & 7)) * 8;
    short8 bf[4];
#pragma unroll
    for (int j = 0; j < 4; ++j)
      bf[j] = *(const short8*)&S[32768 + cur * 16384 + (wn * 64 + j * 16 + fr) * 64 + sl];
    __builtin_amdgcn_s_setprio(1);
#pragma unroll
    for (int i = 0; i < 8; ++i) {
      const short8 af = *(const short8*)&S[cur * 16384 + (wm * 128 + i * 16 + fr) * 64 + sl];
#pragma unroll
      for (int j = 0; j < 4; ++j)
        acc[i][j] = __builtin_amdgcn_mfma_f32_16x16x32_bf16(af, bf[j], acc[i][j], 0, 0, 0);
    }
    __builtin_amdgcn_s_setprio(0);
  };

  // prologue: stage tile 0 and WAIT (required: tt=0 reads B staging).
  loadA(0);
  issueB(0, 0);
  writeA(0);
  asm volatile("s_waitcnt vmcnt(0) lgkmcnt(0)\ns_barrier" ::: "memory");

#pragma unroll 1
  for (int tt = 0; tt < NT; ++tt) {
    const int cur = tt & 1;
    const int nbuf = cur ^ 1;
    const bool pf = (tt + 1 < NT);
    const int nk = (tt + 1) * 64;
    if (pf) {
      loadA(nk);
      issueB(nbuf, nk);
    }
    computeKS(cur, 0);
    if (pf) writeA(nbuf);
    computeKS(cur, 1);
    asm volatile("s_waitcnt vmcnt(0) lgkmcnt(0)\ns_barrier" ::: "memory");
  }
  // loop ended with full drain + barrier -> LDS free for epilogue reuse.

  // epilogue: bias + exact GELU -> LDS (chunk-XOR swizzled) -> coalesced store
  const int ec0 = bcol0 + wn * 64 + fr;
  float bv[4];
#pragma unroll
  for (int j = 0; j < 4; ++j) bv[j] = b1[ec0 + j * 16];
  unsigned short* Wl = S + w * 8192;  // this wave's 128x64 region
#pragma unroll
  for (int i = 0; i < 8; ++i)
#pragma unroll
    for (int j = 0; j < 4; ++j)
#pragma unroll
      for (int r = 0; r < 4; ++r) {
        float v = acc[i][j][r] + bv[j];
        v = 0.5f * v * (1.0f + erff(v * 0.70710678118654752f));
        const int row = i * 16 + kg2 * 4 + r;
        const int col = (j * 16 + fr) ^ (kg2 << 3);  // chunk-XOR swizzle
        Wl[row * 64 + col] = f2bf(v);
      }
  asm volatile("s_waitcnt lgkmcnt(0)" ::: "memory");
#pragma unroll
  for (int pass = 0; pass < 16; ++pass) {  // 16 passes x 8 rows = 128 rows
    const int wr = pass * 8 + (lane >> 3);
    const int ch = (lane & 7) ^ ((wr >> 2) & 3);  // unswizzle chunk
    const short8 v8 = *(const short8*)&Wl[wr * 64 + ch * 8];
    *reinterpret_cast<short8*>(
        &hout[(size_t)(brow0 + wm * 128 + wr) * N1 + bcol0 + wn * 64 + (lane & 7) * 8]) = v8;
  }
}

// GEMM2: out = h @ W2^T + b2 (fp32). 2-phase loop + LDS-transpose epilogue.
__global__ __launch_bounds__(512, 2) void gemm2_kernel(
    const unsigned short* __restrict__ A, const unsigned short* __restrict__ Bw,
    const float* __restrict__ bias, float* __restrict__ out) {
  __shared__ unsigned short S[65536];
  const int t = threadIdx.x;
  const int p = blockIdx.x;
  const int bid = (p & 7) * 32 + (p >> 3);
  const int bm = bid >> 2, bn = bid & 3;
  const int brow0 = bm * 256, bcol0 = bn * 256;
  const int lane = t & 63, w = t >> 6;
  const int wm = w >> 2, wn = w & 3;
  const int fr = lane & 15, kg2 = lane >> 4;

  const int srow = t >> 3;
  const int cg = (t & 7) ^ (srow & 7);
  const unsigned short* aq[4];
  const unsigned short* bq[4];
#pragma unroll
  for (int q = 0; q < 4; ++q) {
    aq[q] = A + (size_t)(brow0 + srow + 64 * q) * K2 + cg * 8;
    bq[q] = Bw + (size_t)(bcol0 + srow + 64 * q) * K2 + cg * 8;
  }
  const int t8 = t * 8;

  floatx4 acc[8][4] = {};
  constexpr int NT = K2 / 64;

  auto stage = [&](int d, int k0) {
#pragma unroll
    for (int q = 0; q < 4; ++q) {
      gload_lds16(aq[q] + k0, &S[d * 16384 + t8 + q * 4096]);
      gload_lds16(bq[q] + k0, &S[32768 + d * 16384 + t8 + q * 4096]);
    }
  };
  auto compute = [&](int cur) {
#pragma unroll
    for (int ks = 0; ks < 2; ++ks) {
      const int sl = ((ks * 4 + kg2) ^ (fr & 7)) * 8;
      short8 bf[4];
#pragma unroll
      for (int j = 0; j < 4; ++j)
        bf[j] = *(const short8*)&S[32768 + cur * 16384 + (wn * 64 + j * 16 + fr) * 64 + sl];
      __builtin_amdgcn_s_setprio(1);
#pragma unroll
      for (int i = 0; i < 8; ++i) {
        const short8 af = *(const short8*)&S[cur * 16384 + (wm * 128 + i * 16 + fr) * 64 + sl];
#pragma unroll
        for (int j = 0; j < 4; ++j)
          acc[i][j] = __builtin_amdgcn_mfma_f32_16x16x32_bf16(af, bf[j], acc[i][j], 0, 0, 0);
      }
      __builtin_amdgcn_s_setprio(0);
    }
  };

  stage(0, 0);
#pragma unroll 1
  for (int it = 0; it < NT - 1; ++it) {
    const int cur = it & 1;
    stage(cur ^ 1, (it + 1) * 64);
    asm volatile("s_waitcnt vmcnt(8)\ns_barrier" ::: "memory");
    compute(cur);
    asm volatile("s_waitcnt lgkmcnt(0)\ns_barrier" ::: "memory");
  }
  asm volatile("s_waitcnt vmcnt(0)\ns_barrier" ::: "memory");
  compute((NT - 1) & 1);
  // other waves may still be reading LDS fragments -> drain + barrier first
  asm volatile("s_waitcnt lgkmcnt(0)\ns_barrier" ::: "memory");

  const int ec0 = bcol0 + wn * 64 + fr;
  float bv[4];
#pragma unroll
  for (int j = 0; j < 4; ++j) bv[j] = bias[ec0 + j * 16];
  float* Wf = reinterpret_cast<float*>(S) + w * 4096;  // 64x64 fp32 per half
#pragma unroll
  for (int ih = 0; ih < 2; ++ih) {
#pragma unroll
    for (int i4 = 0; i4 < 4; ++i4)
#pragma unroll
      for (int j = 0; j < 4; ++j)
#pragma unroll
        for (int r = 0; r < 4; ++r) {
          const int row = i4 * 16 + kg2 * 4 + r;
          const int col = (j * 16 + fr) ^ (kg2 << 2);  // float4-chunk XOR
          Wf[row * 64 + col] = acc[ih * 4 + i4][j][r] + bv[j];
        }
    asm volatile("s_waitcnt lgkmcnt(0)" ::: "memory");
#pragma unroll
    for (int pass = 0; pass < 16; ++pass) {  // 16 passes x 4 rows = 64 rows
      const int wr = pass * 4 + (lane >> 4);
      const int ch = (lane & 15) ^ ((wr >> 2) & 3);
      const floatx4 v4 = *(const floatx4*)&Wf[wr * 64 + ch * 4];
      *reinterpret_cast<floatx4*>(
          &out[(size_t)(brow0 + wm * 128 + ih * 64 + wr) * N2 + bcol0 + wn * 64 +
               (lane & 15) * 4]) = v4;
    }
    if (ih == 0)  // reuse region for second half; own-wave RAW only
      asm volatile("s_waitcnt lgkmcnt(0)" ::: "memory");
  }
}

extern "C" void kernel_launch(void* const* d_in, const int* in_sizes, int n_in,
                              void* d_out, int out_size, void* d_ws, size_t ws_size,
                              hipStream_t stream) {
  const int* idxs = (const int*)d_in[0];
  const float* tok = (const float*)d_in[1];
  const float* W1 = (const float*)d_in[2];
  const float* b1 = (const float*)d_in[3];
  const float* W2 = (const float*)d_in[4];
  const float* b2 = (const float*)d_in[5];
  float* out = (float*)d_out;

  unsigned short* W1b = (unsigned short*)d_ws;                          // 4 MB
  unsigned short* W2b = (unsigned short*)((char*)d_ws + (4u << 20));    // 2 MB
  unsigned short* hbuf = (unsigned short*)((char*)d_ws + (6u << 20));   // 32 MB

  cvt2_kernel<<<3072, 256, 0, stream>>>(W1, W2, W1b, W2b);
  gemm1_fused_kernel<<<256, 512, 0, stream>>>(idxs, tok, W1b, b1, hbuf);
  gemm2_kernel<<<256, 512, 0, stream>>>(hbuf, W2b, b2, out);
}